// Round 1
// baseline (1242.506 us; speedup 1.0000x reference)
//
#include <hip/hip_runtime.h>
#include <hip/hip_bf16.h>
#include <math.h>

#define E_TOT  98304
#define NATOMS 16384
#define NC     49
#define CH     128
#define DEDGE  856
#define NG     600

constexpr double D_DELTA = 5.0 / 599.0;
constexpr float  F_DELTA = (float)D_DELTA;
constexpr float  GCOEF   = (float)(-0.5 / ((2.0 * D_DELTA) * (2.0 * D_DELTA)));
constexpr float  INV_AVG = (float)(1.0 / 23.395238876342773);
constexpr float  FOURPI_INV = 0.07957747154594767f;

#define FMA4(A, W, S) { (A).x = fmaf((S),(W).x,(A).x); (A).y = fmaf((S),(W).y,(A).y); \
                        (A).z = fmaf((S),(W).z,(A).z); (A).w = fmaf((S),(W).w,(A).w); }

__device__ __forceinline__ float siluf(float v) { return v / (1.0f + __expf(-v)); }

// Real spherical harmonics, mirrors reference recurrences exactly (f32).
__device__ __forceinline__ void compute_sh(float x, float y, float z, float* sh) {
    float ct = fminf(fmaxf(z, -1.0f), 1.0f);
    float st = sqrtf(fmaxf(1.0f - ct * ct, 1e-12f));
    float phi = atan2f(y, x);
    float P[7][7];
    P[0][0] = 1.0f;
    #pragma unroll
    for (int m = 1; m < 7; m++) P[m][m] = -(2.0f * m - 1.0f) * st * P[m-1][m-1];
    #pragma unroll
    for (int m = 0; m < 6; m++) P[m+1][m] = (2.0f * m + 1.0f) * ct * P[m][m];
    #pragma unroll
    for (int m = 0; m < 7; m++) {
        #pragma unroll
        for (int l = m + 2; l < 7; l++)
            P[l][m] = ((2.0f*l - 1.0f) * ct * P[l-1][m] - (l + m - 1.0f) * P[l-2][m]) / (float)(l - m);
    }
    const float cp = cosf(phi), sp = sinf(phi);
    #pragma unroll
    for (int l = 0; l < 7; l++) {
        const int base = l * l + l;
        sh[base] = sqrtf((2*l+1) * FOURPI_INV) * P[l][0];
        float ratio = 1.0f;
        float cm = 1.0f, sm = 0.0f;
        #pragma unroll
        for (int m = 1; m <= l; m++) {
            ratio /= (float)((l - m + 1) * (l + m));
            const float cn = cm * cp - sm * sp;
            const float sn = sm * cp + cm * sp;
            cm = cn; sm = sn;
            const float Nlm = sqrtf(2.0f * (2*l+1) * FOURPI_INV * ratio);
            sh[base + m] = Nlm * cm * P[l][m];
            sh[base - m] = Nlm * sm * P[l][m];
        }
    }
}

// MODE 0: write rad (E x 896) + sh (E x 49) to ws (sorted-gather path).
// MODE 1: atomic scatter of coef directly into atom_out (fallback).
template<int MODE>
__global__ __launch_bounds__(256, 2)
void edge_kernel(const float* __restrict__ pos, const int* __restrict__ Z,
                 const int* __restrict__ EI,
                 const float* __restrict__ src_emb, const float* __restrict__ tgt_emb,
                 const float* __restrict__ W1, const float* __restrict__ b1,
                 const float* __restrict__ W2, const float* __restrict__ b2,
                 const float* __restrict__ W3, const float* __restrict__ b3,
                 float* __restrict__ rad_out, float* __restrict__ sh_out,
                 float* __restrict__ atom_out)
{
    __shared__ float s_feat[64][64];
    __shared__ float s_h[64][CH];
    __shared__ float s_dist[64];
    __shared__ int   s_tgt[64];
    __shared__ int   s_zs[64];
    __shared__ int   s_zt[64];
    constexpr int SHSZ = (MODE == 1) ? 64 * NC : 1;
    __shared__ float s_sh[SHSZ];

    const int t  = threadIdx.x;
    const int e0 = blockIdx.x * 64;

    // Phase 0: per-edge geometry + spherical harmonics (threads 0..63)
    if (t < 64) {
        const int e    = e0 + t;
        const int srcA = EI[e];
        const int tgtA = EI[E_TOT + e];
        const float vx = pos[srcA*3+0] - pos[tgtA*3+0];
        const float vy = pos[srcA*3+1] - pos[tgtA*3+1];
        const float vz = pos[srcA*3+2] - pos[tgtA*3+2];
        const float d  = sqrtf(vx*vx + vy*vy + vz*vz + 1e-12f);
        const float inv = 1.0f / d;
        s_dist[t] = d;
        s_tgt[t]  = tgtA;
        s_zs[t]   = Z[srcA];
        s_zt[t]   = Z[tgtA];
        float sh[NC];
        compute_sh(vx*inv, vy*inv, vz*inv, sh);
        if (MODE == 0) {
            #pragma unroll
            for (int i = 0; i < NC; i++) sh_out[e*NC + i] = sh[i];
        } else {
            #pragma unroll
            for (int i = 0; i < NC; i++) s_sh[t*NC + i] = sh[i];
        }
    }
    __syncthreads();

    // Register tile: 4 channels x 8 edges per thread.
    const int cg = t & 31, c0 = cg * 4;
    const int eg = t >> 5, eb = eg * 8;

    // ---- Layer 1: edge_feat(856) @ W1 -> h1(128), feat generated on the fly ----
    float4 acc[8];
    {
        const float4 bb = *(const float4*)&b1[c0];
        #pragma unroll
        for (int j = 0; j < 8; j++) acc[j] = bb;
    }
    for (int k0 = 0; k0 < DEDGE; k0 += 64) {
        const int ksz = (DEDGE - k0 < 64) ? (DEDGE - k0) : 64;
        #pragma unroll
        for (int n = t; n < 64*64; n += 256) {
            const int kk = n & 63, e = n >> 6;
            if (kk < ksz) {
                const int k = k0 + kk;
                float v;
                if (k < NG) {
                    const float dd = s_dist[e] - k * F_DELTA;
                    v = __expf(GCOEF * dd * dd);
                } else if (k < NG + CH) {
                    v = src_emb[s_zs[e]*CH + (k - NG)];
                } else {
                    v = tgt_emb[s_zt[e]*CH + (k - NG - CH)];
                }
                s_feat[e][kk] = v;
            }
        }
        __syncthreads();
        for (int kk = 0; kk < ksz; kk += 4) {
            const float4 w0 = *(const float4*)&W1[(k0+kk+0)*CH + c0];
            const float4 w1 = *(const float4*)&W1[(k0+kk+1)*CH + c0];
            const float4 w2 = *(const float4*)&W1[(k0+kk+2)*CH + c0];
            const float4 w3 = *(const float4*)&W1[(k0+kk+3)*CH + c0];
            #pragma unroll
            for (int j = 0; j < 8; j++) {
                const float4 f = *(const float4*)&s_feat[eb+j][kk];
                FMA4(acc[j], w0, f.x); FMA4(acc[j], w1, f.y);
                FMA4(acc[j], w2, f.z); FMA4(acc[j], w3, f.w);
            }
        }
        __syncthreads();
    }
    #pragma unroll
    for (int j = 0; j < 8; j++) {
        acc[j].x = siluf(acc[j].x); acc[j].y = siluf(acc[j].y);
        acc[j].z = siluf(acc[j].z); acc[j].w = siluf(acc[j].w);
        *(float4*)&s_h[eb+j][c0] = acc[j];
    }
    __syncthreads();

    // ---- Layer 2: h1 @ W2 -> h2 ----
    {
        float4 a2[8];
        const float4 bb = *(const float4*)&b2[c0];
        #pragma unroll
        for (int j = 0; j < 8; j++) a2[j] = bb;
        for (int kk = 0; kk < CH; kk += 4) {
            const float4 w0 = *(const float4*)&W2[(kk+0)*CH + c0];
            const float4 w1 = *(const float4*)&W2[(kk+1)*CH + c0];
            const float4 w2 = *(const float4*)&W2[(kk+2)*CH + c0];
            const float4 w3 = *(const float4*)&W2[(kk+3)*CH + c0];
            #pragma unroll
            for (int j = 0; j < 8; j++) {
                const float4 f = *(const float4*)&s_h[eb+j][kk];
                FMA4(a2[j], w0, f.x); FMA4(a2[j], w1, f.y);
                FMA4(a2[j], w2, f.z); FMA4(a2[j], w3, f.w);
            }
        }
        __syncthreads();  // all reads of h1 complete before overwrite
        #pragma unroll
        for (int j = 0; j < 8; j++) {
            a2[j].x = siluf(a2[j].x); a2[j].y = siluf(a2[j].y);
            a2[j].z = siluf(a2[j].z); a2[j].w = siluf(a2[j].w);
            *(float4*)&s_h[eb+j][c0] = a2[j];
        }
        __syncthreads();
    }

    // ---- Layer 3: h2 @ W3 -> rad(7x128), per l-slice ----
    for (int l = 0; l < 7; l++) {
        float4 a3[8];
        const float4 bb = *(const float4*)&b3[l*CH + c0];
        #pragma unroll
        for (int j = 0; j < 8; j++) a3[j] = bb;
        for (int kk = 0; kk < CH; kk += 4) {
            const float4 w0 = *(const float4*)&W3[(kk+0)*(7*CH) + l*CH + c0];
            const float4 w1 = *(const float4*)&W3[(kk+1)*(7*CH) + l*CH + c0];
            const float4 w2 = *(const float4*)&W3[(kk+2)*(7*CH) + l*CH + c0];
            const float4 w3 = *(const float4*)&W3[(kk+3)*(7*CH) + l*CH + c0];
            #pragma unroll
            for (int j = 0; j < 8; j++) {
                const float4 f = *(const float4*)&s_h[eb+j][kk];
                FMA4(a3[j], w0, f.x); FMA4(a3[j], w1, f.y);
                FMA4(a3[j], w2, f.z); FMA4(a3[j], w3, f.w);
            }
        }
        if (MODE == 0) {
            #pragma unroll
            for (int j = 0; j < 8; j++)
                *(float4*)&rad_out[(size_t)(e0+eb+j)*(7*CH) + l*CH + c0] = a3[j];
        } else {
            #pragma unroll
            for (int j = 0; j < 8; j++) {
                const int a = s_tgt[eb+j];
                float* ob = atom_out + (size_t)a*(NC*CH);
                for (int m = 0; m <= 2*l; m++) {
                    const int i = l*l + m;
                    const float sv = s_sh[(eb+j)*NC + i];
                    atomicAdd(ob + i*CH + c0 + 0, sv * a3[j].x);
                    atomicAdd(ob + i*CH + c0 + 1, sv * a3[j].y);
                    atomicAdd(ob + i*CH + c0 + 2, sv * a3[j].z);
                    atomicAdd(ob + i*CH + c0 + 3, sv * a3[j].w);
                }
            }
        }
    }
}

// ---- counting sort of edges by tgt ----
__global__ void hist_kernel(const int* __restrict__ EI, int* __restrict__ counts) {
    const int e = blockIdx.x * 256 + threadIdx.x;
    if (e < E_TOT) atomicAdd(&counts[EI[E_TOT + e]], 1);
}

__global__ void scan_kernel(const int* counts, int* off, int* cursor) {
    __shared__ int part[1024];
    const int t = threadIdx.x;
    const int base = t * 16;
    int loc[16];
    int s = 0;
    #pragma unroll
    for (int j = 0; j < 16; j++) { const int v = counts[base + j]; loc[j] = s; s += v; }
    part[t] = s;
    __syncthreads();
    for (int o = 1; o < 1024; o <<= 1) {
        const int v = (t >= o) ? part[t - o] : 0;
        __syncthreads();
        part[t] += v;
        __syncthreads();
    }
    const int tb = (t == 0) ? 0 : part[t - 1];
    #pragma unroll
    for (int j = 0; j < 16; j++) { const int v = tb + loc[j]; off[base + j] = v; cursor[base + j] = v; }
    if (t == 0) off[NATOMS] = part[1023];
}

__global__ void scatter_kernel(const int* __restrict__ EI, int* __restrict__ cursor,
                               int* __restrict__ elist) {
    const int e = blockIdx.x * 256 + threadIdx.x;
    if (e < E_TOT) {
        const int a = EI[E_TOT + e];
        const int p = atomicAdd(&cursor[a], 1);
        elist[p] = e;
    }
}

// ---- per-atom finish: /avg_degree, +sphere_emb, RMS norm, *gamma ----
__device__ __forceinline__ void atom_finish(float (&acc)[NC], int a, int t,
        const int* __restrict__ Z, const float* __restrict__ sphere_emb,
        const float* __restrict__ gamma, float* __restrict__ out)
{
    #pragma unroll
    for (int i = 0; i < NC; i++) acc[i] *= INV_AVG;
    acc[0] += sphere_emb[Z[a]*CH + t];
    float ss = 0.0f;
    #pragma unroll
    for (int i = 0; i < NC; i++) ss = fmaf(acc[i], acc[i], ss);
    #pragma unroll
    for (int o = 32; o >= 1; o >>= 1) ss += __shfl_xor(ss, o, 64);
    __shared__ float red[2];
    if ((t & 63) == 0) red[t >> 6] = ss;
    __syncthreads();
    const float tot = red[0] + red[1];
    const float rms = sqrtf(tot * (1.0f / (NC * CH)) + 1e-6f);
    const float g = gamma[t] / rms;
    float* ob = out + (size_t)a * (NC * CH) + t;
    #pragma unroll
    for (int i = 0; i < NC; i++) ob[i*CH] = acc[i] * g;
}

__global__ void atom_kernel(const float* __restrict__ rad, const float* __restrict__ shw,
        const int* __restrict__ off, const int* __restrict__ elist,
        const int* __restrict__ Z, const float* __restrict__ sphere_emb,
        const float* __restrict__ gamma, float* __restrict__ out)
{
    const int a = blockIdx.x, t = threadIdx.x;
    float acc[NC];
    #pragma unroll
    for (int i = 0; i < NC; i++) acc[i] = 0.0f;
    __shared__ float s_shv[NC];
    const int jstart = off[a], jend = off[a + 1];
    for (int j = jstart; j < jend; j++) {
        const int e = elist[j];
        __syncthreads();
        if (t < NC) s_shv[t] = shw[e*NC + t];
        __syncthreads();
        const float* rb = rad + (size_t)e * (7*CH) + t;
        #pragma unroll
        for (int l = 0; l < 7; l++) {
            const float r = rb[l*CH];
            #pragma unroll
            for (int m = 0; m <= 2*l; m++)
                acc[l*l + m] = fmaf(s_shv[l*l + m], r, acc[l*l + m]);
        }
    }
    atom_finish(acc, a, t, Z, sphere_emb, gamma, out);
}

__global__ void normb_kernel(const int* __restrict__ Z, const float* __restrict__ sphere_emb,
        const float* __restrict__ gamma, float* __restrict__ out)
{
    const int a = blockIdx.x, t = threadIdx.x;
    float acc[NC];
    const float* ob = out + (size_t)a * (NC * CH) + t;
    #pragma unroll
    for (int i = 0; i < NC; i++) acc[i] = ob[i*CH];
    atom_finish(acc, a, t, Z, sphere_emb, gamma, out);
}

extern "C" void kernel_launch(void* const* d_in, const int* in_sizes, int n_in,
                              void* d_out, int out_size, void* d_ws, size_t ws_size,
                              hipStream_t stream) {
    const float* pos    = (const float*)d_in[0];
    const int*   Z      = (const int*)d_in[1];
    const int*   EI     = (const int*)d_in[2];
    const float* sphere = (const float*)d_in[3];
    const float* semb   = (const float*)d_in[4];
    const float* temb   = (const float*)d_in[5];
    const float* W1     = (const float*)d_in[6];
    const float* b1     = (const float*)d_in[7];
    const float* W2     = (const float*)d_in[8];
    const float* b2     = (const float*)d_in[9];
    const float* W3     = (const float*)d_in[10];
    const float* b3     = (const float*)d_in[11];
    const float* gamma  = (const float*)d_in[12];
    float* out = (float*)d_out;

    const size_t radB = (size_t)E_TOT * (7*CH) * 4;   // 352,321,536
    const size_t shB  = (size_t)E_TOT * NC * 4;       //  19,267,584
    const size_t offB = (size_t)(NATOMS + 1) * 4;
    const size_t curB = (size_t)NATOMS * 4;
    const size_t elB  = (size_t)E_TOT * 4;
    const size_t need = radB + shB + offB + curB + elB;

    if (ws_size >= need) {
        char* p = (char*)d_ws;
        float* rad = (float*)p;            p += radB;
        float* shw = (float*)p;            p += shB;
        int*   off = (int*)p;              p += offB;
        int*   cur = (int*)p;              p += curB;
        int*   el  = (int*)p;

        hipMemsetAsync(cur, 0, curB, stream);
        hist_kernel<<<E_TOT/256, 256, 0, stream>>>(EI, cur);
        scan_kernel<<<1, 1024, 0, stream>>>(cur, off, cur);  // per-thread read-before-write: safe alias
        scatter_kernel<<<E_TOT/256, 256, 0, stream>>>(EI, cur, el);
        edge_kernel<0><<<E_TOT/64, 256, 0, stream>>>(pos, Z, EI, semb, temb,
                                                     W1, b1, W2, b2, W3, b3,
                                                     rad, shw, nullptr);
        atom_kernel<<<NATOMS, CH, 0, stream>>>(rad, shw, off, el, Z, sphere, gamma, out);
    } else {
        hipMemsetAsync(out, 0, (size_t)out_size * 4, stream);
        edge_kernel<1><<<E_TOT/64, 256, 0, stream>>>(pos, Z, EI, semb, temb,
                                                     W1, b1, W2, b2, W3, b3,
                                                     nullptr, nullptr, out);
        normb_kernel<<<NATOMS, CH, 0, stream>>>(Z, sphere, gamma, out);
    }
}

// Round 4
// 727.130 us; speedup vs baseline: 1.7088x; 1.7088x over previous
//
#include <hip/hip_runtime.h>
#include <hip/hip_bf16.h>
#include <math.h>

#define E_TOT  98304
#define NATOMS 16384
#define NC     49
#define CH     128
#define DEDGE  856
#define NG     600
#define K1     896      // DEDGE padded to 7*128
#define SF     136      // LDS row stride in shorts (128 + 8 pad -> 272 B rows, 16B aligned)

constexpr double D_DELTA = 5.0 / 599.0;
constexpr float  F_DELTA = (float)D_DELTA;
constexpr float  GCOEF   = (float)(-0.5 / ((2.0 * D_DELTA) * (2.0 * D_DELTA)));
constexpr float  INV_AVG = (float)(1.0 / 23.395238876342773);
constexpr float  FOURPI_INV = 0.07957747154594767f;

typedef __attribute__((ext_vector_type(8))) short short8;
typedef __attribute__((ext_vector_type(4))) float f32x4;

__device__ __forceinline__ unsigned short f2bf(float x) {
    union { float f; unsigned u; } v; v.f = x;
    unsigned r = v.u + 0x7FFFu + ((v.u >> 16) & 1u);   // RNE
    return (unsigned short)(r >> 16);
}
__device__ __forceinline__ float bfhi(unsigned u) { return __uint_as_float(u & 0xFFFF0000u); }
__device__ __forceinline__ float bflo(unsigned u) { return __uint_as_float(u << 16); }
__device__ __forceinline__ float siluf(float v) { return v / (1.0f + __expf(-v)); }

// Real spherical harmonics, mirrors reference recurrences exactly (f32).
__device__ __forceinline__ void compute_sh(float x, float y, float z, float* sh) {
    float ct = fminf(fmaxf(z, -1.0f), 1.0f);
    float st = sqrtf(fmaxf(1.0f - ct * ct, 1e-12f));
    float phi = atan2f(y, x);
    float P[7][7];
    P[0][0] = 1.0f;
    #pragma unroll
    for (int m = 1; m < 7; m++) P[m][m] = -(2.0f * m - 1.0f) * st * P[m-1][m-1];
    #pragma unroll
    for (int m = 0; m < 6; m++) P[m+1][m] = (2.0f * m + 1.0f) * ct * P[m][m];
    #pragma unroll
    for (int m = 0; m < 7; m++) {
        #pragma unroll
        for (int l = m + 2; l < 7; l++)
            P[l][m] = ((2.0f*l - 1.0f) * ct * P[l-1][m] - (l + m - 1.0f) * P[l-2][m]) / (float)(l - m);
    }
    const float cp = cosf(phi), sp = sinf(phi);
    #pragma unroll
    for (int l = 0; l < 7; l++) {
        const int base = l * l + l;
        sh[base] = sqrtf((2*l+1) * FOURPI_INV) * P[l][0];
        float ratio = 1.0f;
        float cm = 1.0f, sm = 0.0f;
        #pragma unroll
        for (int m = 1; m <= l; m++) {
            ratio /= (float)((l - m + 1) * (l + m));
            const float cn = cm * cp - sm * sp;
            const float sn = sm * cp + cm * sp;
            cm = cn; sm = sn;
            const float Nlm = sqrtf(2.0f * (2*l+1) * FOURPI_INV * ratio);
            sh[base + m] = Nlm * cm * P[l][m];
            sh[base - m] = Nlm * sm * P[l][m];
        }
    }
}

// ---- weight transpose + bf16 cast: W1T[128][896], W2T[128][128], W3T[896][128] ----
__global__ void prep_kernel(const float* __restrict__ W1, const float* __restrict__ W2,
                            const float* __restrict__ W3,
                            short* __restrict__ W1T, short* __restrict__ W2T,
                            short* __restrict__ W3T)
{
    const int stride = gridDim.x * blockDim.x;
    const int i0 = blockIdx.x * blockDim.x + threadIdx.x;
    for (int i = i0; i < CH * K1; i += stride) {
        const int n = i / K1, k = i - n * K1;
        W1T[i] = (k < DEDGE) ? (short)f2bf(W1[k * CH + n]) : (short)0;
    }
    for (int i = i0; i < CH * CH; i += stride) {
        const int n = i >> 7, k = i & 127;
        W2T[i] = (short)f2bf(W2[k * CH + n]);
    }
    for (int i = i0; i < 7 * CH * CH; i += stride) {
        const int n = i >> 7, k = i & 127;
        W3T[i] = (short)f2bf(W3[k * (7 * CH) + n]);
    }
}

// ---- edge kernel: feat gen + 3-layer MLP via MFMA; writes rad(bf16) + sh(f32) ----
__global__ __launch_bounds__(256, 2)
void edge_kernel(const float* __restrict__ pos, const int* __restrict__ Z,
                 const int* __restrict__ EI,
                 const float* __restrict__ src_emb, const float* __restrict__ tgt_emb,
                 const short* __restrict__ W1T, const float* __restrict__ b1,
                 const short* __restrict__ W2T, const float* __restrict__ b2,
                 const short* __restrict__ W3T, const float* __restrict__ b3,
                 short* __restrict__ rad_out, float* __restrict__ sh_out)
{
    __shared__ short s_feat[64 * SF];   // A-tile chunk [64][128]; reused as C staging in L3
    __shared__ short s_h[64 * SF];      // h1 then h2 [64][128]
    __shared__ float s_dist[64];
    __shared__ int   s_zs[64], s_zt[64];

    const int t  = threadIdx.x;
    const int e0 = blockIdx.x * 64;

    if (t < 64) {
        const int e    = e0 + t;
        const int srcA = EI[e];
        const int tgtA = EI[E_TOT + e];
        const float vx = pos[srcA*3+0] - pos[tgtA*3+0];
        const float vy = pos[srcA*3+1] - pos[tgtA*3+1];
        const float vz = pos[srcA*3+2] - pos[tgtA*3+2];
        const float d  = sqrtf(vx*vx + vy*vy + vz*vz + 1e-12f);
        const float inv = 1.0f / d;
        s_dist[t] = d;
        s_zs[t]   = Z[srcA];
        s_zt[t]   = Z[tgtA];
        float sh[NC];
        compute_sh(vx*inv, vy*inv, vz*inv, sh);
        #pragma unroll
        for (int i = 0; i < NC; i++) sh_out[e*NC + i] = sh[i];
    }
    __syncthreads();

    const int w    = t >> 6;
    const int lane = t & 63;
    const int r16  = lane & 15;          // A-row / B-col / C-col within tile
    const int kg   = (lane >> 4) * 8;    // k-group offset
    const int crow = (lane >> 4) * 4;    // C base row
    const int n0w  = w * 32;             // wave's N slice

    // ================= Layer 1: feat(864) @ W1 =================
    f32x4 acc[4][2];
    #pragma unroll
    for (int nt = 0; nt < 2; ++nt) {
        const float bb = b1[n0w + nt * 16 + r16];
        #pragma unroll
        for (int mt = 0; mt < 4; ++mt) acc[mt][nt] = (f32x4){bb, bb, bb, bb};
    }

    for (int kc = 0; kc < K1; kc += 128) {
        // generate feat chunk [64 edges][128 k] as bf16
        #pragma unroll
        for (int it = 0; it < 4; ++it) {
            const int task = t + it * 256;          // 0..1023
            const int e  = task >> 4;
            const int kl = (task & 15) * 8;
            const float d = s_dist[e];
            const int zs = s_zs[e], zt = s_zt[e];
            unsigned short pk[8];
            #pragma unroll
            for (int j = 0; j < 8; ++j) {
                const int kj = kc + kl + j;
                float v;
                if (kj < NG) { const float dd = d - kj * F_DELTA; v = __expf(GCOEF * dd * dd); }
                else if (kj < NG + CH) v = src_emb[zs * CH + (kj - NG)];
                else if (kj < DEDGE)   v = tgt_emb[zt * CH + (kj - NG - CH)];
                else v = 0.0f;
                pk[j] = f2bf(v);
            }
            uint4 pv;
            pv.x = pk[0] | ((unsigned)pk[1] << 16);
            pv.y = pk[2] | ((unsigned)pk[3] << 16);
            pv.z = pk[4] | ((unsigned)pk[5] << 16);
            pv.w = pk[6] | ((unsigned)pk[7] << 16);
            *(uint4*)&s_feat[e * SF + kl] = pv;
        }
        __syncthreads();

        const short* fb  = &s_feat[r16 * SF + kg];
        const short* wb1 = &W1T[(n0w + r16) * K1 + kc + kg];
        #pragma unroll
        for (int ks = 0; ks < 4; ++ks) {
            short8 av[4], bv[2];
            #pragma unroll
            for (int mt = 0; mt < 4; ++mt) av[mt] = *(const short8*)(fb + mt * 16 * SF + ks * 32);
            #pragma unroll
            for (int nt = 0; nt < 2; ++nt) bv[nt] = *(const short8*)(wb1 + nt * 16 * K1 + ks * 32);
            #pragma unroll
            for (int mt = 0; mt < 4; ++mt)
                #pragma unroll
                for (int nt = 0; nt < 2; ++nt)
                    acc[mt][nt] = __builtin_amdgcn_mfma_f32_16x16x32_bf16(av[mt], bv[nt], acc[mt][nt], 0, 0, 0);
        }
        __syncthreads();
    }

    // silu + stage h1
    #pragma unroll
    for (int mt = 0; mt < 4; ++mt)
        #pragma unroll
        for (int nt = 0; nt < 2; ++nt) {
            const int row = mt * 16 + crow;
            const int c   = n0w + nt * 16 + r16;
            #pragma unroll
            for (int r = 0; r < 4; ++r)
                s_h[(row + r) * SF + c] = (short)f2bf(siluf(acc[mt][nt][r]));
        }
    __syncthreads();

    // ================= Layer 2: h1(128) @ W2 =================
    {
        f32x4 acc2[4][2];
        #pragma unroll
        for (int nt = 0; nt < 2; ++nt) {
            const float bb = b2[n0w + nt * 16 + r16];
            #pragma unroll
            for (int mt = 0; mt < 4; ++mt) acc2[mt][nt] = (f32x4){bb, bb, bb, bb};
        }
        const short* hb  = &s_h[r16 * SF + kg];
        const short* wb2 = &W2T[(n0w + r16) * CH + kg];
        #pragma unroll
        for (int ks = 0; ks < 4; ++ks) {
            short8 av[4], bv[2];
            #pragma unroll
            for (int mt = 0; mt < 4; ++mt) av[mt] = *(const short8*)(hb + mt * 16 * SF + ks * 32);
            #pragma unroll
            for (int nt = 0; nt < 2; ++nt) bv[nt] = *(const short8*)(wb2 + nt * 16 * CH + ks * 32);
            #pragma unroll
            for (int mt = 0; mt < 4; ++mt)
                #pragma unroll
                for (int nt = 0; nt < 2; ++nt)
                    acc2[mt][nt] = __builtin_amdgcn_mfma_f32_16x16x32_bf16(av[mt], bv[nt], acc2[mt][nt], 0, 0, 0);
        }
        __syncthreads();   // all h1 reads done before overwrite
        #pragma unroll
        for (int mt = 0; mt < 4; ++mt)
            #pragma unroll
            for (int nt = 0; nt < 2; ++nt) {
                const int row = mt * 16 + crow;
                const int c   = n0w + nt * 16 + r16;
                #pragma unroll
                for (int r = 0; r < 4; ++r)
                    s_h[(row + r) * SF + c] = (short)f2bf(siluf(acc2[mt][nt][r]));
            }
        __syncthreads();
    }

    // ================= Layer 3: h2(128) @ W3 -> rad[7][128] =================
    {
        const short* hb = &s_h[r16 * SF + kg];
        for (int sl = 0; sl < 7; ++sl) {
            f32x4 acc3[4][2];
            #pragma unroll
            for (int nt = 0; nt < 2; ++nt) {
                const float bb = b3[sl * CH + n0w + nt * 16 + r16];
                #pragma unroll
                for (int mt = 0; mt < 4; ++mt) acc3[mt][nt] = (f32x4){bb, bb, bb, bb};
            }
            const short* wb3 = &W3T[(sl * CH + n0w + r16) * CH + kg];
            #pragma unroll
            for (int ks = 0; ks < 4; ++ks) {
                short8 av[4], bv[2];
                #pragma unroll
                for (int mt = 0; mt < 4; ++mt) av[mt] = *(const short8*)(hb + mt * 16 * SF + ks * 32);
                #pragma unroll
                for (int nt = 0; nt < 2; ++nt) bv[nt] = *(const short8*)(wb3 + nt * 16 * CH + ks * 32);
                #pragma unroll
                for (int mt = 0; mt < 4; ++mt)
                    #pragma unroll
                    for (int nt = 0; nt < 2; ++nt)
                        acc3[mt][nt] = __builtin_amdgcn_mfma_f32_16x16x32_bf16(av[mt], bv[nt], acc3[mt][nt], 0, 0, 0);
            }
            __syncthreads();   // previous slice's copy-out reads are done
            #pragma unroll
            for (int mt = 0; mt < 4; ++mt)
                #pragma unroll
                for (int nt = 0; nt < 2; ++nt) {
                    const int row = mt * 16 + crow;
                    const int c   = n0w + nt * 16 + r16;
                    #pragma unroll
                    for (int r = 0; r < 4; ++r)
                        s_feat[(row + r) * SF + c] = (short)f2bf(acc3[mt][nt][r]);
                }
            __syncthreads();
            // coalesced copy LDS -> rad
            #pragma unroll
            for (int it = 0; it < 4; ++it) {
                const int idx = t + it * 256;      // 0..1023
                const int e = idx >> 4, c8 = (idx & 15) * 8;
                *(short8*)&rad_out[(size_t)(e0 + e) * K1 + sl * CH + c8] =
                    *(const short8*)&s_feat[e * SF + c8];
            }
        }
    }
}

// ---- counting sort of edges by tgt ----
__global__ void hist_kernel(const int* __restrict__ EI, int* __restrict__ counts) {
    const int e = blockIdx.x * 256 + threadIdx.x;
    if (e < E_TOT) atomicAdd(&counts[EI[E_TOT + e]], 1);
}

__global__ void scan_kernel(const int* counts, int* off, int* cursor) {
    __shared__ int part[1024];
    const int t = threadIdx.x;
    const int base = t * 16;
    int loc[16];
    int s = 0;
    #pragma unroll
    for (int j = 0; j < 16; j++) { const int v = counts[base + j]; loc[j] = s; s += v; }
    part[t] = s;
    __syncthreads();
    for (int o = 1; o < 1024; o <<= 1) {
        const int v = (t >= o) ? part[t - o] : 0;
        __syncthreads();
        part[t] += v;
        __syncthreads();
    }
    const int tb = (t == 0) ? 0 : part[t - 1];
    #pragma unroll
    for (int j = 0; j < 16; j++) { const int v = tb + loc[j]; off[base + j] = v; cursor[base + j] = v; }
    if (t == 0) off[NATOMS] = part[1023];
}

__global__ void scatter_kernel(const int* __restrict__ EI, int* __restrict__ cursor,
                               int* __restrict__ elist) {
    const int e = blockIdx.x * 256 + threadIdx.x;
    if (e < E_TOT) {
        const int a = EI[E_TOT + e];
        const int p = atomicAdd(&cursor[a], 1);
        elist[p] = e;
    }
}

// ---- atom kernel: one wave per atom, barrier-free; lane owns channels 2l,2l+1 ----
__global__ __launch_bounds__(256, 2)
void atom_kernel(const short* __restrict__ rad, const float* __restrict__ shw,
                 const int* __restrict__ off, const int* __restrict__ elist,
                 const int* __restrict__ Z, const float* __restrict__ sphere_emb,
                 const float* __restrict__ gamma, float* __restrict__ out)
{
    __shared__ float s_shv[4][52];   // wave-private; no __syncthreads needed
    const int w    = threadIdx.x >> 6;
    const int lane = threadIdx.x & 63;
    const int a    = blockIdx.x * 4 + w;

    float acc0[NC], acc1[NC];
    #pragma unroll
    for (int i = 0; i < NC; i++) { acc0[i] = 0.0f; acc1[i] = 0.0f; }

    const int js = off[a], je = off[a + 1];
    for (int j = js; j < je; ++j) {
        const int e = elist[j];
        if (lane < NC) s_shv[w][lane] = shw[(size_t)e * NC + lane];
        const unsigned* rp = (const unsigned*)&rad[(size_t)e * K1 + 2 * lane];
        unsigned rv[7];
        #pragma unroll
        for (int l = 0; l < 7; ++l) rv[l] = rp[l * 64];   // stride 128 shorts
        #pragma unroll
        for (int l = 0; l < 7; ++l) {
            const float r0 = bflo(rv[l]);
            const float r1 = bfhi(rv[l]);
            #pragma unroll
            for (int m = 0; m <= 2 * l; ++m) {
                const int i = l * l + m;
                const float sv = s_shv[w][i];
                acc0[i] = fmaf(sv, r0, acc0[i]);
                acc1[i] = fmaf(sv, r1, acc1[i]);
            }
        }
    }

    const int z = Z[a];
    const float2 se = *(const float2*)&sphere_emb[z * CH + 2 * lane];
    #pragma unroll
    for (int i = 0; i < NC; i++) { acc0[i] *= INV_AVG; acc1[i] *= INV_AVG; }
    acc0[0] += se.x; acc1[0] += se.y;
    float ss = 0.0f;
    #pragma unroll
    for (int i = 0; i < NC; i++) { ss = fmaf(acc0[i], acc0[i], ss); ss = fmaf(acc1[i], acc1[i], ss); }
    #pragma unroll
    for (int o = 32; o >= 1; o >>= 1) ss += __shfl_xor(ss, o, 64);
    const float rms = sqrtf(ss * (1.0f / (NC * CH)) + 1e-6f);
    const float2 g = *(const float2*)&gamma[2 * lane];
    const float g0 = g.x / rms, g1 = g.y / rms;
    float2* ob = (float2*)(out + (size_t)a * (NC * CH) + 2 * lane);
    #pragma unroll
    for (int i = 0; i < NC; i++) {
        float2 v; v.x = acc0[i] * g0; v.y = acc1[i] * g1;
        ob[(size_t)i * 64] = v;
    }
}

extern "C" void kernel_launch(void* const* d_in, const int* in_sizes, int n_in,
                              void* d_out, int out_size, void* d_ws, size_t ws_size,
                              hipStream_t stream) {
    const float* pos    = (const float*)d_in[0];
    const int*   Z      = (const int*)d_in[1];
    const int*   EI     = (const int*)d_in[2];
    const float* sphere = (const float*)d_in[3];
    const float* semb   = (const float*)d_in[4];
    const float* temb   = (const float*)d_in[5];
    const float* W1     = (const float*)d_in[6];
    const float* b1     = (const float*)d_in[7];
    const float* W2     = (const float*)d_in[8];
    const float* b2     = (const float*)d_in[9];
    const float* W3     = (const float*)d_in[10];
    const float* b3     = (const float*)d_in[11];
    const float* gamma  = (const float*)d_in[12];
    float* out = (float*)d_out;

    char* p = (char*)d_ws;
    short* rad = (short*)p;  p += (size_t)E_TOT * K1 * 2;
    float* shw = (float*)p;  p += (size_t)E_TOT * NC * 4;
    short* W1T = (short*)p;  p += (size_t)CH * K1 * 2;
    short* W2T = (short*)p;  p += (size_t)CH * CH * 2;
    short* W3T = (short*)p;  p += (size_t)7 * CH * CH * 2;
    int* off = (int*)p;      p += (size_t)(NATOMS + 1) * 4;
    int* cur = (int*)p;      p += (size_t)NATOMS * 4;
    int* el  = (int*)p;

    hipMemsetAsync(cur, 0, (size_t)NATOMS * 4, stream);
    hist_kernel<<<E_TOT/256, 256, 0, stream>>>(EI, cur);
    scan_kernel<<<1, 1024, 0, stream>>>(cur, off, cur);
    scatter_kernel<<<E_TOT/256, 256, 0, stream>>>(EI, cur, el);
    prep_kernel<<<512, 256, 0, stream>>>(W1, W2, W3, W1T, W2T, W3T);
    edge_kernel<<<E_TOT/64, 256, 0, stream>>>(pos, Z, EI, semb, temb,
                                              W1T, b1, W2T, b2, W3T, b3,
                                              rad, shw);
    atom_kernel<<<NATOMS/4, 256, 0, stream>>>(rad, shw, off, el, Z, sphere, gamma, out);
}